// Round 13
// baseline (687.110 us; speedup 1.0000x reference)
//
#include <hip/hip_runtime.h>

#define NN 50000
#define EE 800000
#define DD 256
#define NB 196   // ceil(NN/256)

typedef unsigned short u16;
typedef unsigned int u32;

typedef __attribute__((ext_vector_type(8))) short short8;
typedef __attribute__((ext_vector_type(4))) float f32x4;
typedef __attribute__((ext_vector_type(4))) unsigned short u16x4;

__device__ __forceinline__ float b2f(u16 u) {
  union { u32 i; float f; } c; c.i = ((u32)u) << 16; return c.f;
}
__device__ __forceinline__ u16 f2b(float f) {
  union { float f; u32 i; } c; c.f = f;
  u32 u = c.i;
  return (u16)((u + 0x7fffu + ((u >> 16) & 1u)) >> 16);
}
__device__ __forceinline__ float lrelu(float x) { return x > 0.f ? x : 0.2f * x; }
__device__ __forceinline__ float ldf(const void* p, int i, int bf) {
  return bf ? b2f(((const u16*)p)[i]) : ((const float*)p)[i];
}
__device__ __forceinline__ int lde(const void* ei, int idx, int m64) {
  int v = m64 ? (int)((const long long*)ei)[idx] : ((const int*)ei)[idx];
  return v < 0 ? 0 : (v >= NN ? NN - 1 : v);
}
// softmax without online max: shift-invariant, scores bounded -> exact vs ref
__device__ __forceinline__ float cexp(float s) {
  return __expf(fminf(fmaxf(s, -60.f), 60.f));
}

// ---------------- dtype detection (64-lane parallel) ----------------
__global__ void detect_kernel(const void* x, const void* ei, int* flags) {
  int lane = threadIdx.x;
  const u16* xw = (const u16*)x;
  int cnt = 0;
  for (int i = lane; i < 512; i += 64) {
    u16 w = xw[i];
    int e = (w >> 7) & 0xFF;
    if ((e >= 107 && e <= 147) || (w & 0x7FFF) == 0) ++cnt;
  }
  const u32* ew = (const u32*)ei;
  int zc = 0;
  for (int i = 1 + 2 * lane; i < 1024; i += 128)
    if (ew[i] == 0) ++zc;
  #pragma unroll
  for (int off = 1; off < 64; off <<= 1) {
    cnt += __shfl_xor(cnt, off);
    zc += __shfl_xor(zc, off);
  }
  if (lane == 0) {
    flags[0] = (cnt >= 440) ? 1 : 0;
    flags[1] = (zc >= 400) ? 1 : 0;
  }
}

// ---------------- convert x -> internal bf16 ----------------
__global__ __launch_bounds__(256) void convx_kernel(const void* x, const int* flags,
                                                    u16* xb) {
  int bf = flags[0];
  int base = blockIdx.x * 1024 + threadIdx.x * 4;
  if (bf) {
    const u16* s = (const u16*)x;
    #pragma unroll
    for (int j = 0; j < 4; ++j) xb[base + j] = s[base + j];
  } else {
    const float* s = (const float*)x;
    #pragma unroll
    for (int j = 0; j < 4; ++j) xb[base + j] = f2b(s[base + j]);
  }
}

// ---------------- CSR build ----------------
__global__ void hist_kernel(const void* ei, const int* flags, int* cnt) {
  int e = blockIdx.x * 256 + threadIdx.x;
  if (e < EE) atomicAdd(&cnt[lde(ei, EE + e, flags[1])], 1);
}

// -------- parallel 3-phase exclusive scan of deg[NN] -> rowptr[NN+1] --------
__global__ __launch_bounds__(256) void bsum_kernel(const int* __restrict__ deg,
                                                   int* __restrict__ bsum) {
  int i = blockIdx.x * 256 + threadIdx.x;
  int v = (i < NN) ? deg[i] : 0;
  #pragma unroll
  for (int off = 1; off < 64; off <<= 1) v += __shfl_xor(v, off);
  __shared__ int ws[4];
  int lane = threadIdx.x & 63, wid = threadIdx.x >> 6;
  if (lane == 0) ws[wid] = v;
  __syncthreads();
  if (threadIdx.x == 0) bsum[blockIdx.x] = ws[0] + ws[1] + ws[2] + ws[3];
}

__global__ __launch_bounds__(256) void bscan_kernel(const int* __restrict__ bsum,
                                                    int* __restrict__ boff) {
  int t = threadIdx.x;
  int v = (t < NB) ? bsum[t] : 0;
  int iv = v;
  int lane = t & 63, wid = t >> 6;
  #pragma unroll
  for (int off = 1; off < 64; off <<= 1) {
    int u = __shfl_up(iv, off);
    if (lane >= off) iv += u;
  }
  __shared__ int ws[4];
  if (lane == 63) ws[wid] = iv;
  __syncthreads();
  int add = 0;
  for (int w = 0; w < wid; ++w) add += ws[w];
  if (t < NB) boff[t] = iv - v + add;
}

__global__ __launch_bounds__(256) void bwrite_kernel(const int* __restrict__ deg,
                                                     const int* __restrict__ boff,
                                                     int* __restrict__ rowptr) {
  int i = blockIdx.x * 256 + threadIdx.x;
  int v = (i < NN) ? deg[i] : 0;
  int iv = v;
  int lane = threadIdx.x & 63, wid = threadIdx.x >> 6;
  #pragma unroll
  for (int off = 1; off < 64; off <<= 1) {
    int u = __shfl_up(iv, off);
    if (lane >= off) iv += u;
  }
  __shared__ int ws[4];
  if (lane == 63) ws[wid] = iv;
  __syncthreads();
  int add = boff[blockIdx.x];
  for (int w = 0; w < wid; ++w) add += ws[w];
  if (i <= NN) rowptr[i] = iv - v + add;
}

// uses hist counts (cnt[dst]=deg) via atomicSub -> no second memset needed
__global__ void fill_kernel(const void* ei, const int* flags, const int* __restrict__ rowptr,
                            int* __restrict__ cnt, int* __restrict__ col) {
  int e = blockIdx.x * 256 + threadIdx.x;
  if (e < EE) {
    int m64 = flags[1];
    int dst = lde(ei, EE + e, m64);
    int old = atomicSub(&cnt[dst], 1);
    int pos = rowptr[dst] + old - 1;
    if (pos >= 0 && pos < EE) col[pos] = lde(ei, e, m64);
  }
}

// ---------------- weight pack into MFMA B-fragment order ----------------
__global__ void pack_kernel(const void* Wl, const void* Wr, const void* Wlin,
                            const int* flags, u16* wpack) {
  int idx = blockIdx.x * 256 + threadIdx.x;
  if (idx >= 6 * 65536) return;
  int bf = flags[0];
  int m = idx >> 16, e = idx & 65535;
  int layer = (m >= 3) ? 1 : 0, sel = m - layer * 3;
  const void* src = (sel == 0 ? Wl : (sel == 1 ? Wr : Wlin));
  int k = e >> 8, n = e & 255;
  wpack[(m << 16) + ((((k >> 3) << 8) + n) << 3) + (k & 7)] =
      f2b(ldf(src, layer * 65536 + e, bf));
}

// final weights -> 256x48 padded pack
__global__ void fpack_kernel(const void* fWl, const void* fWr, const void* fWlin,
                             const int* flags, u16* fwp) {
  int idx = blockIdx.x * 256 + threadIdx.x;
  if (idx >= 32 * 48 * 8) return;
  int bf = flags[0];
  int j = idx & 7;
  int col = (idx >> 3) % 48;
  int kk = idx / (48 * 8);
  int k = kk * 8 + j;
  float v = 0.f;
  if (col < 20)      v = ldf(fWl, k * 20 + col, bf);
  else if (col < 40) v = ldf(fWr, k * 20 + (col - 20), bf);
  else if (col < 45) v = ldf(fWlin, k * 5 + (col - 40), bf);
  fwp[idx] = f2b(v);
}

// ------- fused GEMM: (M x 256) x (256 x 768), A-resident + LDS-staged B -------------
__global__ __launch_bounds__(256) void gemm_kernel(
    const u16* __restrict__ A, const u16* __restrict__ wpack, const void* blin,
    const int* flags, int layer,
    u16* __restrict__ xl, u16* __restrict__ xr, u16* __restrict__ lp, int M) {
  __shared__ __align__(16) u16 bsh[16384];   // 32 KB: [kk 0..31][col 0..63][j 0..7]
  int wave = threadIdx.x >> 6;
  int lane = threadIdx.x & 63;
  int q = lane >> 4;
  int t = lane & 15;
  int m0 = blockIdx.x * 64 + wave * 16;
  int yh = blockIdx.y;

  int arow = m0 + t;
  if (arow >= M) arow = M - 1;
  const u16* Abase = A + (size_t)arow * DD + q * 8;
  short8 af[8];
  #pragma unroll
  for (int i = 0; i < 8; ++i) af[i] = *(const short8*)(Abase + i * 32);

  int bf = flags[0];

  for (int yi = 0; yi < 6; ++yi) {
    int y = yh * 6 + yi;
    int m = y >> 2;
    int col0 = (y & 3) * 64;
    const u16* wb = wpack + (m << 16);

    __syncthreads();   // previous iteration's LDS reads complete
    #pragma unroll
    for (int itc = 0; itc < 8; ++itc) {
      int chunk = threadIdx.x + itc * 256;    // 0..2047, 16B each
      int kk = chunk >> 6;
      int off = chunk & 63;
      *(uint4*)&bsh[(kk << 9) + (off << 3)] =
          *(const uint4*)(wb + (((kk << 8) + col0) << 3) + (off << 3));
    }
    __syncthreads();

    f32x4 acc[4];
    #pragma unroll
    for (int ns = 0; ns < 4; ++ns) acc[ns] = (f32x4){0.f, 0.f, 0.f, 0.f};

    #pragma unroll
    for (int i = 0; i < 8; ++i) {
      int kk = i * 4 + q;
      const u16* bb = &bsh[(kk << 9) + (t << 3)];
      #pragma unroll
      for (int ns = 0; ns < 4; ++ns) {
        short8 b = *(const short8*)(bb + (ns << 7));
        acc[ns] = __builtin_amdgcn_mfma_f32_16x16x32_bf16(af[i], b, acc[ns], 0, 0, 0);
      }
    }

    u16* dstp = (y < 4) ? xl : (y < 8) ? xr : lp;
    bool isLp = (y >= 8);
    #pragma unroll
    for (int ns = 0; ns < 4; ++ns) {
      int c = col0 + ns * 16 + t;
      float bias = isLp ? ldf(blin, layer * 256 + c, bf) : 0.f;
      #pragma unroll
      for (int r = 0; r < 4; ++r) {
        int row = m0 + q * 4 + r;
        if (row < M) dstp[(size_t)row * DD + c] = f2b(acc[ns][r] + bias);
      }
    }
  }
}

// ---------------- final GEMM via MFMA: emb @ [fWl|fWr|fWlin] (256 -> 48 padded) ------
__global__ __launch_bounds__(256) void fgemm_kernel(
    const u16* __restrict__ A, const u16* __restrict__ fwp, const void* fblin,
    const int* flags, float* __restrict__ zl, float* __restrict__ zr,
    float* __restrict__ lp5, int M) {
  int wave = threadIdx.x >> 6;
  int lane = threadIdx.x & 63;
  int q = lane >> 4;
  int t = lane & 15;
  int m0 = blockIdx.x * 64 + wave * 16;

  f32x4 acc[3];
  #pragma unroll
  for (int ns = 0; ns < 3; ++ns) acc[ns] = (f32x4){0.f, 0.f, 0.f, 0.f};

  int arow = m0 + t;
  if (arow >= M) arow = M - 1;
  const u16* Abase = A + (size_t)arow * DD + q * 8;

  #pragma unroll
  for (int k0 = 0; k0 < DD; k0 += 32) {
    short8 a = *(const short8*)(Abase + k0);
    int kk = (k0 >> 3) + q;
    #pragma unroll
    for (int ns = 0; ns < 3; ++ns) {
      short8 b = *(const short8*)(fwp + (((kk * 48) + ns * 16 + t) << 3));
      acc[ns] = __builtin_amdgcn_mfma_f32_16x16x32_bf16(a, b, acc[ns], 0, 0, 0);
    }
  }

  int bf = flags[0];
  #pragma unroll
  for (int ns = 0; ns < 3; ++ns) {
    int c = ns * 16 + t;
    #pragma unroll
    for (int r = 0; r < 4; ++r) {
      int row = m0 + q * 4 + r;
      if (row < M) {
        float v = acc[ns][r];
        if (c < 20)      zl[row * 20 + c] = v;
        else if (c < 40) zr[row * 20 + (c - 20)] = v;
        else if (c < 45) lp5[row * 5 + (c - 40)] = v + ldf(fblin, c - 40, bf);
      }
    }
  }
}

// ------- GATv2 aggregation: wave/node, no-max softmax, 8-deep gather prefetch -------
// Steady-state loop body identical to the proven round-6 form; prefetch ring adds
// zero per-edge VALU (wave-uniform guard -> s_cbranch). Tail drained with static
// slot indices (main loop advances in multiples of 8).
__global__ __launch_bounds__(64) void agg_kernel(
    const u16* __restrict__ xl, const u16* __restrict__ xr,
    const int* __restrict__ rowptr, const int* __restrict__ col,
    const void* att, const void* bconv, const int* flags, int layer,
    float* __restrict__ cpart) {
  int node = blockIdx.x;
  int lane = threadIdx.x;
  int h = lane >> 4;
  int cb = (lane & 15) * 4;
  int base = h * 64 + cb;
  int bf = flags[0];

  u16x4 r4 = *(const u16x4*)(xr + (size_t)node * DD + base);
  float xrv[4], atv[4];
  #pragma unroll
  for (int j = 0; j < 4; ++j) {
    xrv[j] = b2f(r4[j]);
    atv[j] = ldf(att, layer * 256 + base + j, bf);
  }

  float l = 0.f;
  float acc[4] = {0.f, 0.f, 0.f, 0.f};
  int e0 = rowptr[node], e1 = rowptr[node + 1];
  int n = e1 - e0;

  u16x4 pre[8];
  int head = e0;
  #pragma unroll
  for (int j = 0; j < 8; ++j) {
    if (head < e1) pre[j] = *(const u16x4*)(xl + (size_t)col[head] * DD + base);
    ++head;
  }

  int i = 0;
  for (; i + 8 <= n; i += 8) {
    #pragma unroll
    for (int j = 0; j < 8; ++j) {
      u16x4 cur = pre[j];
      if (head < e1) pre[j] = *(const u16x4*)(xl + (size_t)col[head] * DD + base);
      ++head;
      float x0 = b2f(cur[0]), x1 = b2f(cur[1]), x2 = b2f(cur[2]), x3 = b2f(cur[3]);
      float sp = atv[0] * lrelu(x0 + xrv[0]) + atv[1] * lrelu(x1 + xrv[1]) +
                 atv[2] * lrelu(x2 + xrv[2]) + atv[3] * lrelu(x3 + xrv[3]);
      sp += __shfl_xor(sp, 1);
      sp += __shfl_xor(sp, 2);
      sp += __shfl_xor(sp, 4);
      sp += __shfl_xor(sp, 8);
      float pz = cexp(sp);
      l += pz;
      acc[0] += pz * x0;
      acc[1] += pz * x1;
      acc[2] += pz * x2;
      acc[3] += pz * x3;
    }
  }
  // tail: remaining edges i..n-1 live in pre[0..n-i) (i is a multiple of 8)
  #pragma unroll
  for (int j = 0; j < 8; ++j) {
    if (i + j < n) {
      u16x4 cur = pre[j];
      float x0 = b2f(cur[0]), x1 = b2f(cur[1]), x2 = b2f(cur[2]), x3 = b2f(cur[3]);
      float sp = atv[0] * lrelu(x0 + xrv[0]) + atv[1] * lrelu(x1 + xrv[1]) +
                 atv[2] * lrelu(x2 + xrv[2]) + atv[3] * lrelu(x3 + xrv[3]);
      sp += __shfl_xor(sp, 1);
      sp += __shfl_xor(sp, 2);
      sp += __shfl_xor(sp, 4);
      sp += __shfl_xor(sp, 8);
      float pz = cexp(sp);
      l += pz;
      acc[0] += pz * x0;
      acc[1] += pz * x1;
      acc[2] += pz * x2;
      acc[3] += pz * x3;
    }
  }

  float inv = 1.f / (l + 1e-16f);
  f32x4 outv;
  #pragma unroll
  for (int j = 0; j < 4; ++j)
    outv[j] = acc[j] * inv + ldf(bconv, layer * 256 + base + j, bf);
  *(f32x4*)(cpart + (size_t)node * DD + base) = outv;
}

// ---------------- GraphNorm stats ----------------
__global__ __launch_bounds__(256) void stats_kernel(const float* __restrict__ cpart,
                                                    float* __restrict__ sums) {
  int ch = threadIdx.x;
  int n0 = blockIdx.x * 250, n1 = n0 + 250;
  float s = 0.f, s2 = 0.f;
  for (int n = n0; n < n1; ++n) {
    float x = cpart[(size_t)n * DD + ch];
    s += x; s2 += x * x;
  }
  atomicAdd(&sums[ch], s);
  atomicAdd(&sums[256 + ch], s2);
}

// ---------------- GraphNorm + skip + ELU ----------------
__global__ __launch_bounds__(256) void norm_kernel(
    const float* __restrict__ cpart, const u16* __restrict__ lp,
    const void* gw, const void* gb, const void* gms, const int* flags, int layer,
    const float* __restrict__ sums, u16* __restrict__ emb) {
  int node = blockIdx.x, ch = threadIdx.x;
  int bf = flags[0];
  size_t idx = (size_t)node * DD + ch;
  const float invN = 1.f / (float)NN;
  float mean = sums[ch] * invN;
  float ex2 = sums[256 + ch] * invN;
  float mm = mean * ldf(gms, layer * 256 + ch, bf);
  float var = ex2 - 2.f * mm * mean + mm * mm;
  float x = cpart[idx];
  float y = ldf(gw, layer * 256 + ch, bf) * (x - mm) * rsqrtf(fmaxf(var, 0.f) + 1e-5f) +
            ldf(gb, layer * 256 + ch, bf) + b2f(lp[idx]);
  emb[idx] = f2b(y > 0.f ? y : expm1f(y));
}

// ---------------- final aggregation: 16 edge-lanes/head, no-max softmax -------------
__global__ __launch_bounds__(64) void finagg_kernel(
    const float* __restrict__ zl, const float* __restrict__ zr,
    const int* __restrict__ rowptr, const int* __restrict__ col,
    const void* fatt, const void* fbconv, const int* flags,
    const float* __restrict__ lp5, void* outv) {
  int node = blockIdx.x, lane = threadIdx.x;
  int bf = flags[0];
  int h = lane >> 4, sub = lane & 15;

  float zrv[5], atv[5];
  #pragma unroll
  for (int c = 0; c < 5; ++c) {
    zrv[c] = zr[node * 20 + h * 5 + c];
    atv[c] = ldf(fatt, h * 5 + c, bf);
  }
  float l = 0.f, acc[5] = {0.f, 0.f, 0.f, 0.f, 0.f};
  int e0 = rowptr[node], e1 = rowptr[node + 1];
  for (int e = e0 + sub; e < e1; e += 16) {
    int src = col[e];
    const float* zs = zl + src * 20 + h * 5;
    float zlv[5];
    #pragma unroll
    for (int c = 0; c < 5; ++c) zlv[c] = zs[c];
    float s = 0.f;
    #pragma unroll
    for (int c = 0; c < 5; ++c) s += atv[c] * lrelu(zlv[c] + zrv[c]);
    float pz = cexp(s);
    l += pz;
    #pragma unroll
    for (int c = 0; c < 5; ++c) acc[c] += pz * zlv[c];
  }
  #pragma unroll
  for (int off = 1; off < 16; off <<= 1) {
    l += __shfl_xor(l, off);
    #pragma unroll
    for (int c = 0; c < 5; ++c) acc[c] += __shfl_xor(acc[c], off);
  }
  float inv = 1.f / (l + 1e-16f);
  float v[5];
  #pragma unroll
  for (int c = 0; c < 5; ++c) {
    float tv = acc[c] * inv;
    tv += __shfl_xor(tv, 16);
    tv += __shfl_xor(tv, 32);
    v[c] = tv * 0.25f;
  }
  if (lane == 0) {
    float mx = -3.0e38f;
    #pragma unroll
    for (int c = 0; c < 5; ++c) {
      v[c] += ldf(fbconv, c, bf) + lp5[node * 5 + c];
      mx = fmaxf(mx, v[c]);
    }
    float se = 0.f;
    #pragma unroll
    for (int c = 0; c < 5; ++c) se += __expf(v[c] - mx);
    float lse = mx + __logf(se);
    #pragma unroll
    for (int c = 0; c < 5; ++c) {
      float r = v[c] - lse;
      if (bf) ((u16*)outv)[node * 5 + c] = f2b(r);
      else    ((float*)outv)[node * 5 + c] = r;
    }
  }
}

extern "C" void kernel_launch(void* const* d_in, const int* in_sizes, int n_in,
                              void* d_out, int out_size, void* d_ws, size_t ws_size,
                              hipStream_t stream) {
  (void)in_sizes; (void)n_in; (void)out_size; (void)ws_size;
  const void* x     = d_in[0];
  const void* ei    = d_in[1];
  const void* Wl    = d_in[2];
  const void* Wr    = d_in[3];
  const void* att   = d_in[4];
  const void* bconv = d_in[5];
  const void* Wlin  = d_in[6];
  const void* blin  = d_in[7];
  const void* gnw   = d_in[8];
  const void* gnb   = d_in[9];
  const void* gnms  = d_in[10];
  const void* fWl   = d_in[11];
  const void* fWr   = d_in[12];
  const void* fatt  = d_in[13];
  const void* fbc   = d_in[14];
  const void* fWlin = d_in[15];
  const void* fblin = d_in[16];

  char* p = (char*)d_ws;
  auto take = [&](size_t bytes) {
    char* r = p;
    p += (bytes + 511) & ~(size_t)511;
    return r;
  };
  int* flags   = (int*)take(512);
  int* rowptr  = (int*)take((NN + 1) * sizeof(int));
  int* cnt     = (int*)take(NN * sizeof(int));
  int* colx    = (int*)take(EE * sizeof(int));
  int* bsum    = (int*)take(256 * sizeof(int));
  int* boff    = (int*)take(256 * sizeof(int));
  u16* wpack   = (u16*)take((size_t)6 * 65536 * sizeof(u16));
  u16* fwp     = (u16*)take((size_t)32 * 48 * 8 * sizeof(u16));
  float* sums  = (float*)take(512 * sizeof(float));
  char* unionA = take((size_t)NN * DD * 4);
  u16* xb      = (u16*)unionA;
  float* cpart = (float*)unionA;
  float* zl    = (float*)unionA;
  float* zr    = (float*)(unionA + (size_t)NN * 20 * 4);
  float* lp5   = (float*)(unionA + (size_t)NN * 40 * 4);
  u16* xl      = (u16*)take((size_t)NN * DD * 2);
  u16* xr      = (u16*)take((size_t)NN * DD * 2);
  u16* lp      = (u16*)take((size_t)NN * DD * 2);
  u16* emb     = (u16*)take((size_t)NN * DD * 2);

  detect_kernel<<<dim3(1), dim3(64), 0, stream>>>(x, ei, flags);

  hipMemsetAsync(cnt, 0, NN * sizeof(int), stream);
  hist_kernel<<<dim3((EE + 255) / 256), dim3(256), 0, stream>>>(ei, flags, cnt);
  bsum_kernel<<<dim3(NB), dim3(256), 0, stream>>>(cnt, bsum);
  bscan_kernel<<<dim3(1), dim3(256), 0, stream>>>(bsum, boff);
  bwrite_kernel<<<dim3(NB), dim3(256), 0, stream>>>(cnt, boff, rowptr);
  fill_kernel<<<dim3((EE + 255) / 256), dim3(256), 0, stream>>>(ei, flags, rowptr, cnt, colx);
  pack_kernel<<<dim3(1536), dim3(256), 0, stream>>>(Wl, Wr, Wlin, flags, wpack);
  fpack_kernel<<<dim3(48), dim3(256), 0, stream>>>(fWl, fWr, fWlin, flags, fwp);
  convx_kernel<<<dim3(NN * DD / 1024), dim3(256), 0, stream>>>(x, flags, xb);

  const u16* layerin = xb;
  for (int i = 0; i < 2; ++i) {
    gemm_kernel<<<dim3((NN + 63) / 64, 2), dim3(256), 0, stream>>>(
        layerin, wpack + (size_t)i * 3 * 65536, blin, flags, i, xl, xr, lp, NN);
    agg_kernel<<<dim3(NN), dim3(64), 0, stream>>>(xl, xr, rowptr, colx, att, bconv,
                                                  flags, i, cpart);
    hipMemsetAsync(sums, 0, 512 * sizeof(float), stream);
    stats_kernel<<<dim3(200), dim3(256), 0, stream>>>(cpart, sums);
    norm_kernel<<<dim3(NN), dim3(256), 0, stream>>>(cpart, lp, gnw, gnb, gnms, flags, i,
                                                    sums, emb);
    layerin = emb;
  }
  fgemm_kernel<<<dim3((NN + 63) / 64), dim3(256), 0, stream>>>(emb, fwp, fblin, flags,
                                                               zl, zr, lp5, NN);
  finagg_kernel<<<dim3(NN), dim3(64), 0, stream>>>(zl, zr, rowptr, colx, fatt, fbc, flags,
                                                   lp5, d_out);
}

// Round 14
// 609.705 us; speedup vs baseline: 1.1270x; 1.1270x over previous
//
#include <hip/hip_runtime.h>

#define NN 50000
#define EE 800000
#define DD 256
#define NB 196   // ceil(NN/256)

typedef unsigned short u16;
typedef unsigned int u32;

typedef __attribute__((ext_vector_type(8))) short short8;
typedef __attribute__((ext_vector_type(4))) float f32x4;
typedef __attribute__((ext_vector_type(4))) unsigned short u16x4;

__device__ __forceinline__ float b2f(u16 u) {
  union { u32 i; float f; } c; c.i = ((u32)u) << 16; return c.f;
}
__device__ __forceinline__ u16 f2b(float f) {
  union { float f; u32 i; } c; c.f = f;
  u32 u = c.i;
  return (u16)((u + 0x7fffu + ((u >> 16) & 1u)) >> 16);
}
__device__ __forceinline__ float lrelu(float x) { return x > 0.f ? x : 0.2f * x; }
__device__ __forceinline__ float ldf(const void* p, int i, int bf) {
  return bf ? b2f(((const u16*)p)[i]) : ((const float*)p)[i];
}
__device__ __forceinline__ int lde(const void* ei, int idx, int m64) {
  int v = m64 ? (int)((const long long*)ei)[idx] : ((const int*)ei)[idx];
  return v < 0 ? 0 : (v >= NN ? NN - 1 : v);
}
// softmax without online max: shift-invariant, scores bounded -> exact vs ref
__device__ __forceinline__ float cexp(float s) {
  return __expf(fminf(fmaxf(s, -60.f), 60.f));
}

// ---------------- init: zero cnt + dtype detection (block 0, wave 0) ----------------
__global__ __launch_bounds__(256) void init_kernel(const void* x, const void* ei,
                                                   int* flags, int* cnt) {
  int i = blockIdx.x * 256 + threadIdx.x;
  if (i < NN) cnt[i] = 0;
  if (blockIdx.x == 0 && threadIdx.x < 64) {
    int lane = threadIdx.x;
    const u16* xw = (const u16*)x;
    int c = 0;
    for (int k = lane; k < 512; k += 64) {
      u16 w = xw[k];
      int e = (w >> 7) & 0xFF;
      if ((e >= 107 && e <= 147) || (w & 0x7FFF) == 0) ++c;
    }
    const u32* ew = (const u32*)ei;
    int zc = 0;
    for (int k = 1 + 2 * lane; k < 1024; k += 128)
      if (ew[k] == 0) ++zc;
    #pragma unroll
    for (int off = 1; off < 64; off <<= 1) {
      c += __shfl_xor(c, off);
      zc += __shfl_xor(zc, off);
    }
    if (lane == 0) {
      flags[0] = (c >= 440) ? 1 : 0;
      flags[1] = (zc >= 400) ? 1 : 0;
    }
  }
}

// ---------------- CSR build ----------------
__global__ void hist_kernel(const void* ei, const int* flags, int* cnt) {
  int e = blockIdx.x * 256 + threadIdx.x;
  if (e < EE) atomicAdd(&cnt[lde(ei, EE + e, flags[1])], 1);
}

// -------- parallel 3-phase exclusive scan of deg[NN] -> rowptr[NN+1] --------
__global__ __launch_bounds__(256) void bsum_kernel(const int* __restrict__ deg,
                                                   int* __restrict__ bsum) {
  int i = blockIdx.x * 256 + threadIdx.x;
  int v = (i < NN) ? deg[i] : 0;
  #pragma unroll
  for (int off = 1; off < 64; off <<= 1) v += __shfl_xor(v, off);
  __shared__ int ws[4];
  int lane = threadIdx.x & 63, wid = threadIdx.x >> 6;
  if (lane == 0) ws[wid] = v;
  __syncthreads();
  if (threadIdx.x == 0) bsum[blockIdx.x] = ws[0] + ws[1] + ws[2] + ws[3];
}

__global__ __launch_bounds__(256) void bscan_kernel(const int* __restrict__ bsum,
                                                    int* __restrict__ boff) {
  int t = threadIdx.x;
  int v = (t < NB) ? bsum[t] : 0;
  int iv = v;
  int lane = t & 63, wid = t >> 6;
  #pragma unroll
  for (int off = 1; off < 64; off <<= 1) {
    int u = __shfl_up(iv, off);
    if (lane >= off) iv += u;
  }
  __shared__ int ws[4];
  if (lane == 63) ws[wid] = iv;
  __syncthreads();
  int add = 0;
  for (int w = 0; w < wid; ++w) add += ws[w];
  if (t < NB) boff[t] = iv - v + add;
}

__global__ __launch_bounds__(256) void bwrite_kernel(const int* __restrict__ deg,
                                                     const int* __restrict__ boff,
                                                     int* __restrict__ rowptr) {
  int i = blockIdx.x * 256 + threadIdx.x;
  int v = (i < NN) ? deg[i] : 0;
  int iv = v;
  int lane = threadIdx.x & 63, wid = threadIdx.x >> 6;
  #pragma unroll
  for (int off = 1; off < 64; off <<= 1) {
    int u = __shfl_up(iv, off);
    if (lane >= off) iv += u;
  }
  __shared__ int ws[4];
  if (lane == 63) ws[wid] = iv;
  __syncthreads();
  int add = boff[blockIdx.x];
  for (int w = 0; w < wid; ++w) add += ws[w];
  if (i <= NN) rowptr[i] = iv - v + add;
}

// uses hist counts (cnt[dst]=deg) via atomicSub -> no second memset needed
__global__ void fill_kernel(const void* ei, const int* flags, const int* __restrict__ rowptr,
                            int* __restrict__ cnt, int* __restrict__ col) {
  int e = blockIdx.x * 256 + threadIdx.x;
  if (e < EE) {
    int m64 = flags[1];
    int dst = lde(ei, EE + e, m64);
    int old = atomicSub(&cnt[dst], 1);
    int pos = rowptr[dst] + old - 1;
    if (pos >= 0 && pos < EE) col[pos] = lde(ei, e, m64);
  }
}

// -------- prep: weight pack (MFMA B-frag order) + final-weight pack + x->bf16 --------
// grid 14084: [0,1536) pack wpack, [1536,1584) pack fwp, [1584,14084) convert x.
__global__ __launch_bounds__(256) void prep_kernel(
    const void* Wl, const void* Wr, const void* Wlin,
    const void* fWl, const void* fWr, const void* fWlin,
    const void* x, const int* flags, u16* wpack, u16* fwp, u16* xb) {
  int bf = flags[0];
  int bid = blockIdx.x;
  if (bid < 1536) {
    int idx = bid * 256 + threadIdx.x;
    int m = idx >> 16, e = idx & 65535;
    int layer = (m >= 3) ? 1 : 0, sel = m - layer * 3;
    const void* src = (sel == 0 ? Wl : (sel == 1 ? Wr : Wlin));
    int k = e >> 8, n = e & 255;
    wpack[(m << 16) + ((((k >> 3) << 8) + n) << 3) + (k & 7)] =
        f2b(ldf(src, layer * 65536 + e, bf));
  } else if (bid < 1584) {
    int idx = (bid - 1536) * 256 + threadIdx.x;
    int j = idx & 7;
    int col = (idx >> 3) % 48;
    int kk = idx / (48 * 8);
    int k = kk * 8 + j;
    float v = 0.f;
    if (col < 20)      v = ldf(fWl, k * 20 + col, bf);
    else if (col < 40) v = ldf(fWr, k * 20 + (col - 20), bf);
    else if (col < 45) v = ldf(fWlin, k * 5 + (col - 40), bf);
    fwp[idx] = f2b(v);
  } else {
    int base = (bid - 1584) * 1024 + threadIdx.x * 4;
    if (bf) {
      const u16* s = (const u16*)x;
      #pragma unroll
      for (int j = 0; j < 4; ++j) xb[base + j] = s[base + j];
    } else {
      const float* s = (const float*)x;
      #pragma unroll
      for (int j = 0; j < 4; ++j) xb[base + j] = f2b(s[base + j]);
    }
  }
}

// ------- fused GEMM: (M x 256) x (256 x 768), A-resident + LDS-staged B -------------
// Block-0 prologue zeroes the GraphNorm sums accumulator (replaces a memset dispatch;
// stream-ordered: prior layer's norm already consumed sums).
__global__ __launch_bounds__(256) void gemm_kernel(
    const u16* __restrict__ A, const u16* __restrict__ wpack, const void* blin,
    const int* flags, int layer, float* __restrict__ sums,
    u16* __restrict__ xl, u16* __restrict__ xr, u16* __restrict__ lp, int M) {
  __shared__ __align__(16) u16 bsh[16384];   // 32 KB: [kk 0..31][col 0..63][j 0..7]
  if (blockIdx.x == 0 && blockIdx.y == 0) {
    sums[threadIdx.x] = 0.f;
    sums[threadIdx.x + 256] = 0.f;
  }
  int wave = threadIdx.x >> 6;
  int lane = threadIdx.x & 63;
  int q = lane >> 4;
  int t = lane & 15;
  int m0 = blockIdx.x * 64 + wave * 16;
  int yh = blockIdx.y;

  int arow = m0 + t;
  if (arow >= M) arow = M - 1;
  const u16* Abase = A + (size_t)arow * DD + q * 8;
  short8 af[8];
  #pragma unroll
  for (int i = 0; i < 8; ++i) af[i] = *(const short8*)(Abase + i * 32);

  int bf = flags[0];

  for (int yi = 0; yi < 6; ++yi) {
    int y = yh * 6 + yi;
    int m = y >> 2;
    int col0 = (y & 3) * 64;
    const u16* wb = wpack + (m << 16);

    __syncthreads();   // previous iteration's LDS reads complete
    #pragma unroll
    for (int itc = 0; itc < 8; ++itc) {
      int chunk = threadIdx.x + itc * 256;    // 0..2047, 16B each
      int kk = chunk >> 6;
      int off = chunk & 63;
      *(uint4*)&bsh[(kk << 9) + (off << 3)] =
          *(const uint4*)(wb + (((kk << 8) + col0) << 3) + (off << 3));
    }
    __syncthreads();

    f32x4 acc[4];
    #pragma unroll
    for (int ns = 0; ns < 4; ++ns) acc[ns] = (f32x4){0.f, 0.f, 0.f, 0.f};

    #pragma unroll
    for (int i = 0; i < 8; ++i) {
      int kk = i * 4 + q;
      const u16* bb = &bsh[(kk << 9) + (t << 3)];
      #pragma unroll
      for (int ns = 0; ns < 4; ++ns) {
        short8 b = *(const short8*)(bb + (ns << 7));
        acc[ns] = __builtin_amdgcn_mfma_f32_16x16x32_bf16(af[i], b, acc[ns], 0, 0, 0);
      }
    }

    u16* dstp = (y < 4) ? xl : (y < 8) ? xr : lp;
    bool isLp = (y >= 8);
    #pragma unroll
    for (int ns = 0; ns < 4; ++ns) {
      int c = col0 + ns * 16 + t;
      float bias = isLp ? ldf(blin, layer * 256 + c, bf) : 0.f;
      #pragma unroll
      for (int r = 0; r < 4; ++r) {
        int row = m0 + q * 4 + r;
        if (row < M) dstp[(size_t)row * DD + c] = f2b(acc[ns][r] + bias);
      }
    }
  }
}

// ---------------- final GEMM via MFMA: emb @ [fWl|fWr|fWlin] (256 -> 48 padded) ------
__global__ __launch_bounds__(256) void fgemm_kernel(
    const u16* __restrict__ A, const u16* __restrict__ fwp, const void* fblin,
    const int* flags, float* __restrict__ zl, float* __restrict__ zr,
    float* __restrict__ lp5, int M) {
  int wave = threadIdx.x >> 6;
  int lane = threadIdx.x & 63;
  int q = lane >> 4;
  int t = lane & 15;
  int m0 = blockIdx.x * 64 + wave * 16;

  f32x4 acc[3];
  #pragma unroll
  for (int ns = 0; ns < 3; ++ns) acc[ns] = (f32x4){0.f, 0.f, 0.f, 0.f};

  int arow = m0 + t;
  if (arow >= M) arow = M - 1;
  const u16* Abase = A + (size_t)arow * DD + q * 8;

  #pragma unroll
  for (int k0 = 0; k0 < DD; k0 += 32) {
    short8 a = *(const short8*)(Abase + k0);
    int kk = (k0 >> 3) + q;
    #pragma unroll
    for (int ns = 0; ns < 3; ++ns) {
      short8 b = *(const short8*)(fwp + (((kk * 48) + ns * 16 + t) << 3));
      acc[ns] = __builtin_amdgcn_mfma_f32_16x16x32_bf16(a, b, acc[ns], 0, 0, 0);
    }
  }

  int bf = flags[0];
  #pragma unroll
  for (int ns = 0; ns < 3; ++ns) {
    int c = ns * 16 + t;
    #pragma unroll
    for (int r = 0; r < 4; ++r) {
      int row = m0 + q * 4 + r;
      if (row < M) {
        float v = acc[ns][r];
        if (c < 20)      zl[row * 20 + c] = v;
        else if (c < 40) zr[row * 20 + (c - 20)] = v;
        else if (c < 45) lp5[row * 5 + (c - 40)] = v + ldf(fblin, c - 40, bf);
      }
    }
  }
}

// ------- GATv2 aggregation (round-12 proven form): wave/node, no-max softmax --------
// Output cpart is bf16 now (halves write + downstream read traffic).
__global__ __launch_bounds__(64) void agg_kernel(
    const u16* __restrict__ xl, const u16* __restrict__ xr,
    const int* __restrict__ rowptr, const int* __restrict__ col,
    const void* att, const void* bconv, const int* flags, int layer,
    u16* __restrict__ cpart) {
  int node = blockIdx.x;
  int lane = threadIdx.x;
  int h = lane >> 4;
  int cb = (lane & 15) * 4;
  int base = h * 64 + cb;
  int bf = flags[0];

  u16x4 r4 = *(const u16x4*)(xr + (size_t)node * DD + base);
  float xrv[4], atv[4];
  #pragma unroll
  for (int j = 0; j < 4; ++j) {
    xrv[j] = b2f(r4[j]);
    atv[j] = ldf(att, layer * 256 + base + j, bf);
  }

  float l = 0.f;
  float acc[4] = {0.f, 0.f, 0.f, 0.f};
  int e0 = rowptr[node], e1 = rowptr[node + 1];
  for (int e = e0; e < e1; ++e) {
    int src = col[e];
    u16x4 s4 = *(const u16x4*)(xl + (size_t)src * DD + base);
    float x0 = b2f(s4[0]), x1 = b2f(s4[1]), x2 = b2f(s4[2]), x3 = b2f(s4[3]);
    float sp = atv[0] * lrelu(x0 + xrv[0]) + atv[1] * lrelu(x1 + xrv[1]) +
               atv[2] * lrelu(x2 + xrv[2]) + atv[3] * lrelu(x3 + xrv[3]);
    sp += __shfl_xor(sp, 1);
    sp += __shfl_xor(sp, 2);
    sp += __shfl_xor(sp, 4);
    sp += __shfl_xor(sp, 8);
    float pz = cexp(sp);
    l += pz;
    acc[0] += pz * x0;
    acc[1] += pz * x1;
    acc[2] += pz * x2;
    acc[3] += pz * x3;
  }
  float inv = 1.f / (l + 1e-16f);
  u16x4 outw;
  #pragma unroll
  for (int j = 0; j < 4; ++j)
    outw[j] = f2b(acc[j] * inv + ldf(bconv, layer * 256 + base + j, bf));
  *(u16x4*)(cpart + (size_t)node * DD + base) = outw;
}

// ---------------- GraphNorm stats (bf16 input) ----------------
__global__ __launch_bounds__(256) void stats_kernel(const u16* __restrict__ cpart,
                                                    float* __restrict__ sums) {
  int ch = threadIdx.x;
  int n0 = blockIdx.x * 250, n1 = n0 + 250;
  float s = 0.f, s2 = 0.f;
  for (int n = n0; n < n1; ++n) {
    float x = b2f(cpart[(size_t)n * DD + ch]);
    s += x; s2 += x * x;
  }
  atomicAdd(&sums[ch], s);
  atomicAdd(&sums[256 + ch], s2);
}

// ---------------- GraphNorm + skip + ELU (bf16 cpart) ----------------
__global__ __launch_bounds__(256) void norm_kernel(
    const u16* __restrict__ cpart, const u16* __restrict__ lp,
    const void* gw, const void* gb, const void* gms, const int* flags, int layer,
    const float* __restrict__ sums, u16* __restrict__ emb) {
  int node = blockIdx.x, ch = threadIdx.x;
  int bf = flags[0];
  size_t idx = (size_t)node * DD + ch;
  const float invN = 1.f / (float)NN;
  float mean = sums[ch] * invN;
  float ex2 = sums[256 + ch] * invN;
  float mm = mean * ldf(gms, layer * 256 + ch, bf);
  float var = ex2 - 2.f * mm * mean + mm * mm;
  float x = b2f(cpart[idx]);
  float y = ldf(gw, layer * 256 + ch, bf) * (x - mm) * rsqrtf(fmaxf(var, 0.f) + 1e-5f) +
            ldf(gb, layer * 256 + ch, bf) + b2f(lp[idx]);
  emb[idx] = f2b(y > 0.f ? y : expm1f(y));
}

// ---------------- final aggregation: 16 edge-lanes/head, no-max softmax -------------
__global__ __launch_bounds__(64) void finagg_kernel(
    const float* __restrict__ zl, const float* __restrict__ zr,
    const int* __restrict__ rowptr, const int* __restrict__ col,
    const void* fatt, const void* fbconv, const int* flags,
    const float* __restrict__ lp5, void* outv) {
  int node = blockIdx.x, lane = threadIdx.x;
  int bf = flags[0];
  int h = lane >> 4, sub = lane & 15;

  float zrv[5], atv[5];
  #pragma unroll
  for (int c = 0; c < 5; ++c) {
    zrv[c] = zr[node * 20 + h * 5 + c];
    atv[c] = ldf(fatt, h * 5 + c, bf);
  }
  float l = 0.f, acc[5] = {0.f, 0.f, 0.f, 0.f, 0.f};
  int e0 = rowptr[node], e1 = rowptr[node + 1];
  for (int e = e0 + sub; e < e1; e += 16) {
    int src = col[e];
    const float* zs = zl + src * 20 + h * 5;
    float zlv[5];
    #pragma unroll
    for (int c = 0; c < 5; ++c) zlv[c] = zs[c];
    float s = 0.f;
    #pragma unroll
    for (int c = 0; c < 5; ++c) s += atv[c] * lrelu(zlv[c] + zrv[c]);
    float pz = cexp(s);
    l += pz;
    #pragma unroll
    for (int c = 0; c < 5; ++c) acc[c] += pz * zlv[c];
  }
  #pragma unroll
  for (int off = 1; off < 16; off <<= 1) {
    l += __shfl_xor(l, off);
    #pragma unroll
    for (int c = 0; c < 5; ++c) acc[c] += __shfl_xor(acc[c], off);
  }
  float inv = 1.f / (l + 1e-16f);
  float v[5];
  #pragma unroll
  for (int c = 0; c < 5; ++c) {
    float tv = acc[c] * inv;
    tv += __shfl_xor(tv, 16);
    tv += __shfl_xor(tv, 32);
    v[c] = tv * 0.25f;
  }
  if (lane == 0) {
    float mx = -3.0e38f;
    #pragma unroll
    for (int c = 0; c < 5; ++c) {
      v[c] += ldf(fbconv, c, bf) + lp5[node * 5 + c];
      mx = fmaxf(mx, v[c]);
    }
    float se = 0.f;
    #pragma unroll
    for (int c = 0; c < 5; ++c) se += __expf(v[c] - mx);
    float lse = mx + __logf(se);
    #pragma unroll
    for (int c = 0; c < 5; ++c) {
      float r = v[c] - lse;
      if (bf) ((u16*)outv)[node * 5 + c] = f2b(r);
      else    ((float*)outv)[node * 5 + c] = r;
    }
  }
}

extern "C" void kernel_launch(void* const* d_in, const int* in_sizes, int n_in,
                              void* d_out, int out_size, void* d_ws, size_t ws_size,
                              hipStream_t stream) {
  (void)in_sizes; (void)n_in; (void)out_size; (void)ws_size;
  const void* x     = d_in[0];
  const void* ei    = d_in[1];
  const void* Wl    = d_in[2];
  const void* Wr    = d_in[3];
  const void* att   = d_in[4];
  const void* bconv = d_in[5];
  const void* Wlin  = d_in[6];
  const void* blin  = d_in[7];
  const void* gnw   = d_in[8];
  const void* gnb   = d_in[9];
  const void* gnms  = d_in[10];
  const void* fWl   = d_in[11];
  const void* fWr   = d_in[12];
  const void* fatt  = d_in[13];
  const void* fbc   = d_in[14];
  const void* fWlin = d_in[15];
  const void* fblin = d_in[16];

  char* p = (char*)d_ws;
  auto take = [&](size_t bytes) {
    char* r = p;
    p += (bytes + 511) & ~(size_t)511;
    return r;
  };
  int* flags   = (int*)take(512);
  int* rowptr  = (int*)take((NN + 1) * sizeof(int));
  int* cnt     = (int*)take(NN * sizeof(int));
  int* colx    = (int*)take(EE * sizeof(int));
  int* bsum    = (int*)take(256 * sizeof(int));
  int* boff    = (int*)take(256 * sizeof(int));
  u16* wpack   = (u16*)take((size_t)6 * 65536 * sizeof(u16));
  u16* fwp     = (u16*)take((size_t)32 * 48 * 8 * sizeof(u16));
  float* sums  = (float*)take(512 * sizeof(float));
  // unionA: xb (layer-1 GEMM input) -> cpart bf16 (agg out) -> zl/zr/lp5 (final).
  char* unionA = take((size_t)NN * DD * 4);
  u16* xb      = (u16*)unionA;
  u16* cpart   = (u16*)unionA;
  float* zl    = (float*)unionA;
  float* zr    = (float*)(unionA + (size_t)NN * 20 * 4);
  float* lp5   = (float*)(unionA + (size_t)NN * 40 * 4);
  u16* xl      = (u16*)take((size_t)NN * DD * 2);
  u16* xr      = (u16*)take((size_t)NN * DD * 2);
  u16* lp      = (u16*)take((size_t)NN * DD * 2);
  u16* emb     = (u16*)take((size_t)NN * DD * 2);

  init_kernel<<<dim3(NB), dim3(256), 0, stream>>>(x, ei, flags, cnt);
  hist_kernel<<<dim3((EE + 255) / 256), dim3(256), 0, stream>>>(ei, flags, cnt);
  bsum_kernel<<<dim3(NB), dim3(256), 0, stream>>>(cnt, bsum);
  bscan_kernel<<<dim3(1), dim3(256), 0, stream>>>(bsum, boff);
  bwrite_kernel<<<dim3(NB), dim3(256), 0, stream>>>(cnt, boff, rowptr);
  fill_kernel<<<dim3((EE + 255) / 256), dim3(256), 0, stream>>>(ei, flags, rowptr, cnt, colx);
  prep_kernel<<<dim3(1584 + NN * DD / 1024), dim3(256), 0, stream>>>(
      Wl, Wr, Wlin, fWl, fWr, fWlin, x, flags, wpack, fwp, xb);

  const u16* layerin = xb;
  for (int i = 0; i < 2; ++i) {
    gemm_kernel<<<dim3((NN + 63) / 64, 2), dim3(256), 0, stream>>>(
        layerin, wpack + (size_t)i * 3 * 65536, blin, flags, i, sums, xl, xr, lp, NN);
    agg_kernel<<<dim3(NN), dim3(64), 0, stream>>>(xl, xr, rowptr, colx, att, bconv,
                                                  flags, i, cpart);
    stats_kernel<<<dim3(200), dim3(256), 0, stream>>>(cpart, sums);
    norm_kernel<<<dim3(NN), dim3(256), 0, stream>>>(cpart, lp, gnw, gnb, gnms, flags, i,
                                                    sums, emb);
    layerin = emb;
  }
  fgemm_kernel<<<dim3((NN + 63) / 64), dim3(256), 0, stream>>>(emb, fwp, fblin, flags,
                                                               zl, zr, lp5, NN);
  finagg_kernel<<<dim3(NN), dim3(64), 0, stream>>>(zl, zr, rowptr, colx, fatt, fbc, flags,
                                                   lp5, d_out);
}